// Round 7
// baseline (228.837 us; speedup 1.0000x reference)
//
#include <hip/hip_runtime.h>

#define LSEQ 4096
#define EMB  1024
#define NH   16
#define HD   64

typedef __attribute__((ext_vector_type(8)))  __bf16 bf16x8;
typedef __attribute__((ext_vector_type(4)))  float f32x4;
typedef __attribute__((ext_vector_type(16))) float f32x16;
typedef __attribute__((ext_vector_type(8)))  unsigned short u16x8;
typedef __attribute__((ext_vector_type(4)))  unsigned short u16x4;
typedef __attribute__((ext_vector_type(4)))  unsigned int u32x4;

__device__ __forceinline__ unsigned short f2bf(float f) {
    union { float f; unsigned u; } v; v.f = f;
    unsigned r = v.u + 0x7fffu + ((v.u >> 16) & 1u);
    return (unsigned short)(r >> 16);
}

__device__ __forceinline__ unsigned cvt_pk_bf16(float a, float b) {
    unsigned r;
    asm("v_cvt_pk_bf16_f32 %0, %1, %2" : "=v"(r) : "v"(a), "v"(b));
    return r;
}

// exchange: x'[0:31]=x, x'[32:63]=y[l-32]; y'[0:31]=x[l+32], y'[32:63]=y
__device__ __forceinline__ void plswap(unsigned &x, unsigned &y) {
    asm volatile("v_permlane32_swap_b32 %0, %1" : "+v"(x), "+v"(y));
}

__device__ __forceinline__ f32x4 mfma16(u16x8 a, u16x8 b, f32x4 c) {
    return __builtin_amdgcn_mfma_f32_16x16x32_bf16(
        __builtin_bit_cast(bf16x8, a), __builtin_bit_cast(bf16x8, b), c, 0, 0, 0);
}

__device__ __forceinline__ f32x16 mfma32(u16x8 a, u16x8 b, f32x16 c) {
    return __builtin_amdgcn_mfma_f32_32x32x16_bf16(
        __builtin_bit_cast(bf16x8, a), __builtin_bit_cast(bf16x8, b), c, 0, 0, 0);
}

__device__ __forceinline__ void gload16(const void* g, void* l) {
    __builtin_amdgcn_global_load_lds((const __attribute__((address_space(1))) unsigned int*)g,
                                     (__attribute__((address_space(3))) unsigned int*)l,
                                     16, 0, 0);
}

// ---------------- fused fp32 -> bf16 convert ----------------
#define NXC (LSEQ * EMB / 4)
#define NAC (3 * EMB * EMB / 4)
#define NPC (EMB * EMB / 4)
__global__ __launch_bounds__(256) void cvt_all(const float* __restrict__ x,
                                               const float* __restrict__ wa,
                                               const float* __restrict__ wp,
                                               unsigned short* __restrict__ out) {
    int i = blockIdx.x * 256 + threadIdx.x;
    if (i >= NXC + NAC + NPC) return;
    const float* src;
    if (i < NXC)             src = x + (size_t)i * 4;
    else if (i < NXC + NAC)  src = wa + (size_t)(i - NXC) * 4;
    else                     src = wp + (size_t)(i - NXC - NAC) * 4;
    f32x4 v = *(const f32x4*)src;
    u16x4 o;
    o[0] = f2bf(v[0]); o[1] = f2bf(v[1]); o[2] = f2bf(v[2]); o[3] = f2bf(v[3]);
    *(u16x4*)(out + (size_t)i * 4) = o;
}

// ---------------- QKV GEMM: C[M=L,N=3E] = X[L,E] * Wattn^T, scatter epilogue ----------------
// Q pre-scaled by 0.125*log2(e): attention softmax runs in exp2 domain.
__global__ __launch_bounds__(256, 2) void gemm_qkv(const unsigned short* __restrict__ A,
                                                   const unsigned short* __restrict__ B,
                                                   unsigned short* __restrict__ Qo,
                                                   unsigned short* __restrict__ Ko,
                                                   unsigned short* __restrict__ Vto) {
    __shared__ unsigned short As[128 * 32];
    __shared__ unsigned short Bs[128 * 32];
    const int tid = threadIdx.x;
    const int lane = tid & 63;
    const int wv = tid >> 6;
    const int wm = wv >> 1, wn = wv & 1;
    const int li = lane & 15, g = lane >> 4;
    const int m0 = blockIdx.y * 128, n0 = blockIdx.x * 128;
    f32x4 acc[4][4] = {};
    for (int k0 = 0; k0 < EMB; k0 += 32) {
        #pragma unroll
        for (int c = 0; c < 2; ++c) {
            const int o = c * 4096 + tid * 16;
            const int r = o >> 6, cb = o & 63;
            gload16((const char*)A + ((size_t)(m0 + r) * EMB + k0) * 2 + cb, (char*)As + o);
            gload16((const char*)B + ((size_t)(n0 + r) * EMB + k0) * 2 + cb, (char*)Bs + o);
        }
        __syncthreads();
        u16x8 af[4], bfr[4];
        #pragma unroll
        for (int mb = 0; mb < 4; ++mb)
            af[mb] = *(const u16x8*)(As + (wm * 64 + mb * 16 + li) * 32 + g * 8);
        #pragma unroll
        for (int nb = 0; nb < 4; ++nb)
            bfr[nb] = *(const u16x8*)(Bs + (wn * 64 + nb * 16 + li) * 32 + g * 8);
        #pragma unroll
        for (int mb = 0; mb < 4; ++mb)
            #pragma unroll
            for (int nb = 0; nb < 4; ++nb)
                acc[mb][nb] = mfma16(af[mb], bfr[nb], acc[mb][nb]);
        __syncthreads();
    }
    for (int mb = 0; mb < 4; ++mb) {
        for (int nb = 0; nb < 4; ++nb) {
            for (int r = 0; r < 4; ++r) {
                const int m = m0 + wm * 64 + mb * 16 + g * 4 + r;
                const int n = n0 + wn * 64 + nb * 16 + li;
                const float v = acc[mb][nb][r];
                if (n < EMB) {
                    Qo[((size_t)(n >> 6) * LSEQ + m) * HD + (n & 63)] = f2bf(v * 0.1803368801111244f);
                } else if (n < 2 * EMB) {
                    const int c = n - EMB;
                    Ko[((size_t)(c >> 6) * LSEQ + m) * HD + (c & 63)] = f2bf(v);
                } else {
                    const int c = n - 2 * EMB;
                    Vto[((size_t)(c >> 6) * HD + (c & 63)) * LSEQ + m] = f2bf(v);
                }
            }
        }
    }
}

// ---------------- flash attention (causal): zero-LDS, zero-barrier ----------------
// 128 thr = 2 waves; wave w owns q rows [qt*64 + w*32, +32).
// K/V read directly from global (L2-resident: 2 heads per XCD via dispatch decode).
// grid 1024: d0 -> xcd = d0&7, head = xcd + 8*((d0>>3)&1), qt = 63 - (d0>>4)  (heavy-first LPT).
__global__ __launch_bounds__(128, 3) void attn_fwd(const unsigned short* __restrict__ Q,
                                                   const unsigned short* __restrict__ K,
                                                   const unsigned short* __restrict__ Vt,
                                                   unsigned short* __restrict__ Y) {
    const int d0 = blockIdx.x;
    const int head = (d0 & 7) + 8 * ((d0 >> 3) & 1);
    const int qt = 63 - (d0 >> 4);
    const int w = threadIdx.x >> 6, lane = threadIdx.x & 63;
    const int li = lane & 31, hf = lane >> 5;
    const int q0 = qt * 64 + w * 32;
    const int qrow = q0 + li;                       // this lane's q (softmax state)
    const unsigned short* Kh = K + (size_t)head * LSEQ * HD;
    const unsigned short* Vh = Vt + (size_t)head * HD * LSEQ;

    u16x8 bq[4];
    #pragma unroll
    for (int ks = 0; ks < 4; ++ks)
        bq[ks] = *(const u16x8*)(Q + ((size_t)head * LSEQ + qrow) * HD + ks * 16 + hf * 8);

    float m_i = -1e30f, l_i = 0.f;
    f32x16 oA = {}, oB = {};
    const int jmax = qt;

    for (int j = 0; j <= jmax; ++j) {
        const unsigned short* kb = Kh + (size_t)j * 64 * HD;
        // ---- K fragments direct from L2 ----
        u16x8 ka[8];
        #pragma unroll
        for (int ks = 0; ks < 4; ++ks) {
            ka[2 * ks]     = *(const u16x8*)(kb + (size_t)li * HD + (2 * ks + hf) * 8);
            ka[2 * ks + 1] = *(const u16x8*)(kb + (size_t)(32 + li) * HD + (2 * ks + hf) * 8);
        }
        // ---- QK^T swapped: lane holds S[kv(reg)][q=li] ----
        f32x16 sA = {}, sB = {};
        __builtin_amdgcn_s_setprio(1);
        #pragma unroll
        for (int ks = 0; ks < 4; ++ks) {
            sA = mfma32(ka[2 * ks],     bq[ks], sA);
            sB = mfma32(ka[2 * ks + 1], bq[ks], sB);
        }
        __builtin_amdgcn_s_setprio(0);
        // ---- V fragments issued now; latency covered by softmax ----
        const unsigned short* vb = Vh + j * 64;
        u16x8 va[4], vc[4];
        #pragma unroll
        for (int c = 0; c < 4; ++c) {
            va[c] = *(const u16x8*)(vb + (size_t)li * LSEQ + (2 * c + hf) * 8);
            vc[c] = *(const u16x8*)(vb + (size_t)(32 + li) * LSEQ + (2 * c + hf) * 8);
        }
        if (j == jmax) {   // causal mask (diagonal tile only)
            #pragma unroll
            for (int r = 0; r < 16; ++r) {
                const int kvl = j * 64 + (r & 3) + 8 * (r >> 2) + 4 * hf;
                if (kvl > qrow)      sA[r] = -1e30f;
                if (kvl + 32 > qrow) sB[r] = -1e30f;
            }
        }
        // ---- softmax: in-lane reduce + one half-swap ----
        float c0 = sA[0], c1 = sA[1], c2 = sA[2], c3 = sA[3];
        #pragma unroll
        for (int r = 4; r < 16; r += 4) {
            c0 = fmaxf(c0, sA[r]);     c1 = fmaxf(c1, sA[r + 1]);
            c2 = fmaxf(c2, sA[r + 2]); c3 = fmaxf(c3, sA[r + 3]);
        }
        #pragma unroll
        for (int r = 0; r < 16; r += 4) {
            c0 = fmaxf(c0, sB[r]);     c1 = fmaxf(c1, sB[r + 1]);
            c2 = fmaxf(c2, sB[r + 2]); c3 = fmaxf(c3, sB[r + 3]);
        }
        float mt = fmaxf(fmaxf(c0, c1), fmaxf(c2, c3));
        mt = fmaxf(mt, __shfl_xor(mt, 32));
        const bool need = !__all(mt - m_i <= 8.0f);   // T13 (exp2 domain, P<=256)
        float al = 1.0f;
        if (need) {
            const float mn = fmaxf(m_i, mt);
            al = exp2f(m_i - mn);
            m_i = mn;
        }
        float s0 = 0.f, s1 = 0.f;
        unsigned uA[8], uB[8];
        #pragma unroll
        for (int wd = 0; wd < 8; ++wd) {
            const float a0 = exp2f(sA[2 * wd] - m_i), a1 = exp2f(sA[2 * wd + 1] - m_i);
            const float b0 = exp2f(sB[2 * wd] - m_i), b1 = exp2f(sB[2 * wd + 1] - m_i);
            s0 += a0 + a1; s1 += b0 + b1;
            uA[wd] = cvt_pk_bf16(a0, a1);
            uB[wd] = cvt_pk_bf16(b0, b1);
        }
        float sum = s0 + s1;
        sum += __shfl_xor(sum, 32);
        l_i = l_i * al + sum;
        if (need) {
            #pragma unroll
            for (int r = 0; r < 16; ++r) {
                const int ql = (r & 3) + 8 * (r >> 2) + 4 * hf;
                const float af = __shfl(al, ql);
                oA[r] *= af; oB[r] *= af;
            }
        }
        // ---- P redistribution in-register (T12) ----
        plswap(uA[0], uA[2]); plswap(uA[1], uA[3]);
        plswap(uA[4], uA[6]); plswap(uA[5], uA[7]);
        plswap(uB[0], uB[2]); plswap(uB[1], uB[3]);
        plswap(uB[4], uB[6]); plswap(uB[5], uB[7]);
        const u32x4 wA0 = {uA[0], uA[1], uA[2], uA[3]};
        const u32x4 wA1 = {uA[4], uA[5], uA[6], uA[7]};
        const u32x4 wB0 = {uB[0], uB[1], uB[2], uB[3]};
        const u32x4 wB1 = {uB[4], uB[5], uB[6], uB[7]};
        const u16x8 ap0 = __builtin_bit_cast(u16x8, wA0);
        const u16x8 ap1 = __builtin_bit_cast(u16x8, wA1);
        const u16x8 ap2 = __builtin_bit_cast(u16x8, wB0);
        const u16x8 ap3 = __builtin_bit_cast(u16x8, wB1);
        // ---- PV ----
        __builtin_amdgcn_s_setprio(1);
        oA = mfma32(ap0, va[0], oA);
        oA = mfma32(ap1, va[1], oA);
        oA = mfma32(ap2, va[2], oA);
        oA = mfma32(ap3, va[3], oA);
        oB = mfma32(ap0, vc[0], oB);
        oB = mfma32(ap1, vc[1], oB);
        oB = mfma32(ap2, vc[2], oB);
        oB = mfma32(ap3, vc[3], oB);
        __builtin_amdgcn_s_setprio(0);
    }
    const float linv = 1.0f / l_i;
    #pragma unroll
    for (int r = 0; r < 16; ++r) {
        const int ql = (r & 3) + 8 * (r >> 2) + 4 * hf;
        const float gl = __shfl(linv, ql);
        Y[(size_t)(q0 + ql) * EMB + head * HD + li]      = f2bf(oA[r] * gl);
        Y[(size_t)(q0 + ql) * EMB + head * HD + 32 + li] = f2bf(oB[r] * gl);
    }
}

// ---------------- proj GEMM: out[L,E] fp32 = Y[L,E] * Wproj^T ----------------
__global__ __launch_bounds__(256, 2) void gemm_proj(const unsigned short* __restrict__ A,
                                                    const unsigned short* __restrict__ B,
                                                    float* __restrict__ C) {
    __shared__ unsigned short As[128 * 32];
    __shared__ unsigned short Bs[128 * 32];
    const int tid = threadIdx.x;
    const int lane = tid & 63;
    const int wv = tid >> 6;
    const int wm = wv >> 1, wn = wv & 1;
    const int li = lane & 15, g = lane >> 4;
    const int m0 = blockIdx.y * 128, n0 = blockIdx.x * 128;
    f32x4 acc[4][4] = {};
    for (int k0 = 0; k0 < EMB; k0 += 32) {
        #pragma unroll
        for (int c = 0; c < 2; ++c) {
            const int o = c * 4096 + tid * 16;
            const int r = o >> 6, cb = o & 63;
            gload16((const char*)A + ((size_t)(m0 + r) * EMB + k0) * 2 + cb, (char*)As + o);
            gload16((const char*)B + ((size_t)(n0 + r) * EMB + k0) * 2 + cb, (char*)Bs + o);
        }
        __syncthreads();
        u16x8 af[4], bfr[4];
        #pragma unroll
        for (int mb = 0; mb < 4; ++mb)
            af[mb] = *(const u16x8*)(As + (wm * 64 + mb * 16 + li) * 32 + g * 8);
        #pragma unroll
        for (int nb = 0; nb < 4; ++nb)
            bfr[nb] = *(const u16x8*)(Bs + (wn * 64 + nb * 16 + li) * 32 + g * 8);
        #pragma unroll
        for (int mb = 0; mb < 4; ++mb)
            #pragma unroll
            for (int nb = 0; nb < 4; ++nb)
                acc[mb][nb] = mfma16(af[mb], bfr[nb], acc[mb][nb]);
        __syncthreads();
    }
    for (int mb = 0; mb < 4; ++mb)
        for (int nb = 0; nb < 4; ++nb)
            for (int r = 0; r < 4; ++r) {
                const int m = m0 + wm * 64 + mb * 16 + g * 4 + r;
                const int n = n0 + wn * 64 + nb * 16 + li;
                C[(size_t)m * EMB + n] = acc[mb][nb][r];
            }
}

extern "C" void kernel_launch(void* const* d_in, const int* in_sizes, int n_in,
                              void* d_out, int out_size, void* d_ws, size_t ws_size,
                              hipStream_t stream) {
    const float* x      = (const float*)d_in[0];
    const float* w_attn = (const float*)d_in[1];
    const float* w_proj = (const float*)d_in[2];
    float* out = (float*)d_out;

    unsigned short* ws  = (unsigned short*)d_ws;
    unsigned short* xb  = ws;
    unsigned short* wab = xb + (size_t)LSEQ * EMB;
    unsigned short* wpb = wab + (size_t)3 * EMB * EMB;
    unsigned short* Qb  = wpb + (size_t)EMB * EMB;
    unsigned short* Kb  = Qb + (size_t)LSEQ * EMB;
    unsigned short* Vtb = Kb + (size_t)LSEQ * EMB;
    unsigned short* Yb  = Vtb + (size_t)LSEQ * EMB;

    const int ntot = NXC + NAC + NPC;
    cvt_all<<<(ntot + 255) / 256, 256, 0, stream>>>(x, w_attn, w_proj, xb);
    gemm_qkv<<<dim3(3 * EMB / 128, LSEQ / 128), 256, 0, stream>>>(xb, wab, Qb, Kb, Vtb);
    attn_fwd<<<dim3(1024), 128, 0, stream>>>(Qb, Kb, Vtb, Yb);
    gemm_proj<<<dim3(EMB / 128, LSEQ / 128), 256, 0, stream>>>(Yb, wpb, out);
}

// Round 8
// 168.172 us; speedup vs baseline: 1.3607x; 1.3607x over previous
//
#include <hip/hip_runtime.h>

#define LSEQ 4096
#define EMB  1024
#define NH   16
#define HD   64

typedef __attribute__((ext_vector_type(8)))  __bf16 bf16x8;
typedef __attribute__((ext_vector_type(4)))  float f32x4;
typedef __attribute__((ext_vector_type(16))) float f32x16;
typedef __attribute__((ext_vector_type(8)))  unsigned short u16x8;
typedef __attribute__((ext_vector_type(4)))  unsigned short u16x4;
typedef __attribute__((ext_vector_type(4)))  unsigned int u32x4;

__device__ __forceinline__ unsigned short f2bf(float f) {
    union { float f; unsigned u; } v; v.f = f;
    unsigned r = v.u + 0x7fffu + ((v.u >> 16) & 1u);
    return (unsigned short)(r >> 16);
}

__device__ __forceinline__ unsigned cvt_pk_bf16(float a, float b) {
    unsigned r;
    asm("v_cvt_pk_bf16_f32 %0, %1, %2" : "=v"(r) : "v"(a), "v"(b));
    return r;
}

// exchange: x'[0:31]=x, x'[32:63]=y[l-32]; y'[0:31]=x[l+32], y'[32:63]=y
__device__ __forceinline__ void plswap(unsigned &x, unsigned &y) {
    asm volatile("v_permlane32_swap_b32 %0, %1" : "+v"(x), "+v"(y));
}

__device__ __forceinline__ f32x4 mfma16(u16x8 a, u16x8 b, f32x4 c) {
    return __builtin_amdgcn_mfma_f32_16x16x32_bf16(
        __builtin_bit_cast(bf16x8, a), __builtin_bit_cast(bf16x8, b), c, 0, 0, 0);
}

__device__ __forceinline__ f32x16 mfma32(u16x8 a, u16x8 b, f32x16 c) {
    return __builtin_amdgcn_mfma_f32_32x32x16_bf16(
        __builtin_bit_cast(bf16x8, a), __builtin_bit_cast(bf16x8, b), c, 0, 0, 0);
}

__device__ __forceinline__ void gload16(const void* g, void* l) {
    __builtin_amdgcn_global_load_lds((const __attribute__((address_space(1))) unsigned int*)g,
                                     (__attribute__((address_space(3))) unsigned int*)l,
                                     16, 0, 0);
}

// ---------------- fused fp32 -> bf16 convert ----------------
#define NXC (LSEQ * EMB / 4)
#define NAC (3 * EMB * EMB / 4)
#define NPC (EMB * EMB / 4)
__global__ __launch_bounds__(256) void cvt_all(const float* __restrict__ x,
                                               const float* __restrict__ wa,
                                               const float* __restrict__ wp,
                                               unsigned short* __restrict__ out) {
    int i = blockIdx.x * 256 + threadIdx.x;
    if (i >= NXC + NAC + NPC) return;
    const float* src;
    if (i < NXC)             src = x + (size_t)i * 4;
    else if (i < NXC + NAC)  src = wa + (size_t)(i - NXC) * 4;
    else                     src = wp + (size_t)(i - NXC - NAC) * 4;
    f32x4 v = *(const f32x4*)src;
    u16x4 o;
    o[0] = f2bf(v[0]); o[1] = f2bf(v[1]); o[2] = f2bf(v[2]); o[3] = f2bf(v[3]);
    *(u16x4*)(out + (size_t)i * 4) = o;
}

// ---------------- QKV GEMM: C[M=L,N=3E] = X[L,E] * Wattn^T, scatter epilogue ----------------
// Q pre-scaled by 0.125*log2(e): attention softmax runs in exp2 domain.
__global__ __launch_bounds__(256, 2) void gemm_qkv(const unsigned short* __restrict__ A,
                                                   const unsigned short* __restrict__ B,
                                                   unsigned short* __restrict__ Qo,
                                                   unsigned short* __restrict__ Ko,
                                                   unsigned short* __restrict__ Vto) {
    __shared__ unsigned short As[128 * 32];
    __shared__ unsigned short Bs[128 * 32];
    const int tid = threadIdx.x;
    const int lane = tid & 63;
    const int wv = tid >> 6;
    const int wm = wv >> 1, wn = wv & 1;
    const int li = lane & 15, g = lane >> 4;
    const int m0 = blockIdx.y * 128, n0 = blockIdx.x * 128;
    f32x4 acc[4][4] = {};
    for (int k0 = 0; k0 < EMB; k0 += 32) {
        #pragma unroll
        for (int c = 0; c < 2; ++c) {
            const int o = c * 4096 + tid * 16;
            const int r = o >> 6, cb = o & 63;
            gload16((const char*)A + ((size_t)(m0 + r) * EMB + k0) * 2 + cb, (char*)As + o);
            gload16((const char*)B + ((size_t)(n0 + r) * EMB + k0) * 2 + cb, (char*)Bs + o);
        }
        __syncthreads();
        u16x8 af[4], bfr[4];
        #pragma unroll
        for (int mb = 0; mb < 4; ++mb)
            af[mb] = *(const u16x8*)(As + (wm * 64 + mb * 16 + li) * 32 + g * 8);
        #pragma unroll
        for (int nb = 0; nb < 4; ++nb)
            bfr[nb] = *(const u16x8*)(Bs + (wn * 64 + nb * 16 + li) * 32 + g * 8);
        #pragma unroll
        for (int mb = 0; mb < 4; ++mb)
            #pragma unroll
            for (int nb = 0; nb < 4; ++nb)
                acc[mb][nb] = mfma16(af[mb], bfr[nb], acc[mb][nb]);
        __syncthreads();
    }
    for (int mb = 0; mb < 4; ++mb) {
        for (int nb = 0; nb < 4; ++nb) {
            for (int r = 0; r < 4; ++r) {
                const int m = m0 + wm * 64 + mb * 16 + g * 4 + r;
                const int n = n0 + wn * 64 + nb * 16 + li;
                const float v = acc[mb][nb][r];
                if (n < EMB) {
                    Qo[((size_t)(n >> 6) * LSEQ + m) * HD + (n & 63)] = f2bf(v * 0.1803368801111244f);
                } else if (n < 2 * EMB) {
                    const int c = n - EMB;
                    Ko[((size_t)(c >> 6) * LSEQ + m) * HD + (c & 63)] = f2bf(v);
                } else {
                    const int c = n - 2 * EMB;
                    Vto[((size_t)(c >> 6) * HD + (c & 63)) * LSEQ + m] = f2bf(v);
                }
            }
        }
    }
}

// ---------------- flash attention (causal): chunk-major LDS, covered drain ----------------
// grid 512, 256 thr = 4 waves; supertile = 128 q rows; wave w owns rows [s*128+w*32, +32).
// Decode: xcd = d0&7, idx = d0>>3: head = 2*xcd + (idx&1), s = 31 - (idx>>1) (heavy-first LPT,
// 2 heads per XCD -> KV L2-resident). LDS: 2 x (K 8KB + V 8KB) chunk-major [8][64][16B].
// Per tile: STAGE(next) issue -> compute(cur) -> __syncthreads (vmcnt drain covered by compute).
__global__ __launch_bounds__(256, 2) void attn_fwd(const unsigned short* __restrict__ Q,
                                                   const unsigned short* __restrict__ K,
                                                   const unsigned short* __restrict__ Vt,
                                                   unsigned short* __restrict__ Y) {
    __shared__ char LB[32768];   // [buf 0/1][ K 8KB | V 8KB ]
    const int d0 = blockIdx.x;
    const int xcd = d0 & 7, idx = d0 >> 3;
    const int head = 2 * xcd + (idx & 1);
    const int s = 31 - (idx >> 1);
    const int q0 = s * 128;
    const int jmaxb = 2 * s + 1;
    const int tid = threadIdx.x, lane = tid & 63, w = tid >> 6;
    const int li = lane & 31, hf = lane >> 5;
    const int qw0 = q0 + w * 32;
    const int qrow = qw0 + li;                 // this lane's q
    const unsigned short* Kh = K + (size_t)head * LSEQ * HD;
    const unsigned short* Vh = Vt + (size_t)head * HD * LSEQ;

    // Q fragments (read once)
    u16x8 bq[4];
    #pragma unroll
    for (int ks = 0; ks < 4; ++ks)
        bq[ks] = *(const u16x8*)(Q + ((size_t)head * LSEQ + qrow) * HD + ks * 16 + hf * 8);

    float m_i = 0.f, l_i = 0.f;                // exp2 domain; bias starts at 0
    f32x16 oA = {}, oB = {};

    // stage tile j into buffer b: wave w writes K chunks {w, w+4}, V chunks {w, w+4}
    // LDS chunk-major: [chunk][row][16B]; dest linear per wave (base + lane*16).
    #define STAGE(j_, b_) do {                                                          \
        char* bk_ = LB + (b_) * 16384;                                                  \
        char* bv_ = bk_ + 8192;                                                         \
        const unsigned short* kg_ = Kh + (size_t)(j_) * 64 * HD;                        \
        const unsigned short* vg_ = Vh + (j_) * 64;                                     \
        gload16(kg_ + (size_t)lane * HD + w * 8,          bk_ + w * 1024 + lane * 16);  \
        gload16(kg_ + (size_t)lane * HD + (w + 4) * 8,    bk_ + (w + 4) * 1024 + lane * 16); \
        gload16(vg_ + (size_t)lane * LSEQ + w * 8,        bv_ + w * 1024 + lane * 16);  \
        gload16(vg_ + (size_t)lane * LSEQ + (w + 4) * 8,  bv_ + (w + 4) * 1024 + lane * 16); \
    } while (0)

    STAGE(0, 0);
    __syncthreads();
    for (int t = 0; t <= jmaxb; ++t) {
        const int cur = t & 1;
        if (t < jmaxb) STAGE(t + 1, cur ^ 1);     // issue early; drained at end barrier
        const int kbase = t * 64;
        if (kbase <= qw0 + 31) {                  // wave-uniform activity
            const char* Kb = LB + cur * 16384;
            const char* Vb = Kb + 8192;
            // ---- QK^T swapped, acc pre-biased with -m_i (folds softmax subtract) ----
            f32x16 sA, sB;
            const float nm = -m_i;
            #pragma unroll
            for (int r = 0; r < 16; ++r) { sA[r] = nm; sB[r] = nm; }
            __builtin_amdgcn_s_setprio(1);
            #pragma unroll
            for (int ks = 0; ks < 4; ++ks) {
                const u16x8 ka0 = *(const u16x8*)(Kb + (2 * ks + hf) * 1024 + li * 16);
                const u16x8 ka1 = *(const u16x8*)(Kb + (2 * ks + hf) * 1024 + 512 + li * 16);
                sA = mfma32(ka0, bq[ks], sA);
                sB = mfma32(ka1, bq[ks], sB);
            }
            __builtin_amdgcn_s_setprio(0);
            if (kbase + 63 > qw0) {               // causal mask (diagonal tiles only)
                #pragma unroll
                for (int r = 0; r < 16; ++r) {
                    const int kvl = kbase + (r & 3) + 8 * (r >> 2) + 4 * hf;
                    if (kvl > qrow)      sA[r] = -1e30f;
                    if (kvl + 32 > qrow) sB[r] = -1e30f;
                }
            }
            // ---- tile max (biased domain): in-lane + one half-swap ----
            float c0 = fmaxf(sA[0], sA[1]), c1 = fmaxf(sA[2], sA[3]);
            float c2 = fmaxf(sB[0], sB[1]), c3 = fmaxf(sB[2], sB[3]);
            #pragma unroll
            for (int r = 4; r < 16; r += 4) {
                c0 = fmaxf(c0, fmaxf(sA[r], sA[r + 1]));
                c1 = fmaxf(c1, fmaxf(sA[r + 2], sA[r + 3]));
                c2 = fmaxf(c2, fmaxf(sB[r], sB[r + 1]));
                c3 = fmaxf(c3, fmaxf(sB[r + 2], sB[r + 3]));
            }
            float mt = fmaxf(fmaxf(c0, c1), fmaxf(c2, c3));
            mt = fmaxf(mt, __shfl_xor(mt, 32));
            const bool need = !__all(mt <= 8.0f);   // T13: growth beyond 2^8
            float sum;
            unsigned uA[8], uB[8];
            if (!need) {
                // common path: no subtract at all
                float s0 = 0.f, s1 = 0.f;
                #pragma unroll
                for (int wd = 0; wd < 8; ++wd) {
                    const float a0 = exp2f(sA[2 * wd]), a1 = exp2f(sA[2 * wd + 1]);
                    const float b0 = exp2f(sB[2 * wd]), b1 = exp2f(sB[2 * wd + 1]);
                    s0 += a0 + a1; s1 += b0 + b1;
                    uA[wd] = cvt_pk_bf16(a0, a1);
                    uB[wd] = cvt_pk_bf16(b0, b1);
                }
                sum = s0 + s1;
            } else {
                // rescale path: new ref = m_i + mt
                const float al = exp2f(-mt);
                m_i += mt;
                l_i *= al;
                #pragma unroll
                for (int r = 0; r < 16; ++r) {
                    const int ql = (r & 3) + 8 * (r >> 2) + 4 * hf;
                    const float af = __shfl(al, ql);
                    oA[r] *= af; oB[r] *= af;
                }
                float s0 = 0.f, s1 = 0.f;
                #pragma unroll
                for (int wd = 0; wd < 8; ++wd) {
                    const float a0 = exp2f(sA[2 * wd] - mt), a1 = exp2f(sA[2 * wd + 1] - mt);
                    const float b0 = exp2f(sB[2 * wd] - mt), b1 = exp2f(sB[2 * wd + 1] - mt);
                    s0 += a0 + a1; s1 += b0 + b1;
                    uA[wd] = cvt_pk_bf16(a0, a1);
                    uB[wd] = cvt_pk_bf16(b0, b1);
                }
                sum = s0 + s1;
            }
            sum += __shfl_xor(sum, 32);
            l_i += sum;
            // ---- P redistribution in-register (T12) ----
            plswap(uA[0], uA[2]); plswap(uA[1], uA[3]);
            plswap(uA[4], uA[6]); plswap(uA[5], uA[7]);
            plswap(uB[0], uB[2]); plswap(uB[1], uB[3]);
            plswap(uB[4], uB[6]); plswap(uB[5], uB[7]);
            const u32x4 wA0 = {uA[0], uA[1], uA[2], uA[3]};
            const u32x4 wA1 = {uA[4], uA[5], uA[6], uA[7]};
            const u32x4 wB0 = {uB[0], uB[1], uB[2], uB[3]};
            const u32x4 wB1 = {uB[4], uB[5], uB[6], uB[7]};
            const u16x8 ap0 = __builtin_bit_cast(u16x8, wA0);   // kv  0..15
            const u16x8 ap1 = __builtin_bit_cast(u16x8, wA1);   // kv 16..31
            const u16x8 ap2 = __builtin_bit_cast(u16x8, wB0);   // kv 32..47
            const u16x8 ap3 = __builtin_bit_cast(u16x8, wB1);   // kv 48..63
            // ---- PV: V chunk-major reads (1 addr reg + imm offsets) ----
            const u16x8 va0 = *(const u16x8*)(Vb + hf * 1024 + li * 16);
            const u16x8 va1 = *(const u16x8*)(Vb + (2 + hf) * 1024 + li * 16);
            const u16x8 va2 = *(const u16x8*)(Vb + (4 + hf) * 1024 + li * 16);
            const u16x8 va3 = *(const u16x8*)(Vb + (6 + hf) * 1024 + li * 16);
            const u16x8 vc0 = *(const u16x8*)(Vb + hf * 1024 + 512 + li * 16);
            const u16x8 vc1 = *(const u16x8*)(Vb + (2 + hf) * 1024 + 512 + li * 16);
            const u16x8 vc2 = *(const u16x8*)(Vb + (4 + hf) * 1024 + 512 + li * 16);
            const u16x8 vc3 = *(const u16x8*)(Vb + (6 + hf) * 1024 + 512 + li * 16);
            __builtin_amdgcn_s_setprio(1);
            oA = mfma32(ap0, va0, oA);
            oA = mfma32(ap1, va1, oA);
            oA = mfma32(ap2, va2, oA);
            oA = mfma32(ap3, va3, oA);
            oB = mfma32(ap0, vc0, oB);
            oB = mfma32(ap1, vc1, oB);
            oB = mfma32(ap2, vc2, oB);
            oB = mfma32(ap3, vc3, oB);
            __builtin_amdgcn_s_setprio(0);
        }
        __syncthreads();   // readers done + prefetch drained (covered by compute)
    }
    #undef STAGE
    const float linv = 1.0f / l_i;
    #pragma unroll
    for (int r = 0; r < 16; ++r) {
        const int ql = (r & 3) + 8 * (r >> 2) + 4 * hf;
        const float gl = __shfl(linv, ql);
        Y[(size_t)(qw0 + ql) * EMB + head * HD + li]      = f2bf(oA[r] * gl);
        Y[(size_t)(qw0 + ql) * EMB + head * HD + 32 + li] = f2bf(oB[r] * gl);
    }
}

// ---------------- proj GEMM: out[L,E] fp32 = Y[L,E] * Wproj^T ----------------
__global__ __launch_bounds__(256, 2) void gemm_proj(const unsigned short* __restrict__ A,
                                                    const unsigned short* __restrict__ B,
                                                    float* __restrict__ C) {
    __shared__ unsigned short As[128 * 32];
    __shared__ unsigned short Bs[128 * 32];
    const int tid = threadIdx.x;
    const int lane = tid & 63;
    const int wv = tid >> 6;
    const int wm = wv >> 1, wn = wv & 1;
    const int li = lane & 15, g = lane >> 4;
    const int m0 = blockIdx.y * 128, n0 = blockIdx.x * 128;
    f32x4 acc[4][4] = {};
    for (int k0 = 0; k0 < EMB; k0 += 32) {
        #pragma unroll
        for (int c = 0; c < 2; ++c) {
            const int o = c * 4096 + tid * 16;
            const int r = o >> 6, cb = o & 63;
            gload16((const char*)A + ((size_t)(m0 + r) * EMB + k0) * 2 + cb, (char*)As + o);
            gload16((const char*)B + ((size_t)(n0 + r) * EMB + k0) * 2 + cb, (char*)Bs + o);
        }
        __syncthreads();
        u16x8 af[4], bfr[4];
        #pragma unroll
        for (int mb = 0; mb < 4; ++mb)
            af[mb] = *(const u16x8*)(As + (wm * 64 + mb * 16 + li) * 32 + g * 8);
        #pragma unroll
        for (int nb = 0; nb < 4; ++nb)
            bfr[nb] = *(const u16x8*)(Bs + (wn * 64 + nb * 16 + li) * 32 + g * 8);
        #pragma unroll
        for (int mb = 0; mb < 4; ++mb)
            #pragma unroll
            for (int nb = 0; nb < 4; ++nb)
                acc[mb][nb] = mfma16(af[mb], bfr[nb], acc[mb][nb]);
        __syncthreads();
    }
    for (int mb = 0; mb < 4; ++mb)
        for (int nb = 0; nb < 4; ++nb)
            for (int r = 0; r < 4; ++r) {
                const int m = m0 + wm * 64 + mb * 16 + g * 4 + r;
                const int n = n0 + wn * 64 + nb * 16 + li;
                C[(size_t)m * EMB + n] = acc[mb][nb][r];
            }
}

extern "C" void kernel_launch(void* const* d_in, const int* in_sizes, int n_in,
                              void* d_out, int out_size, void* d_ws, size_t ws_size,
                              hipStream_t stream) {
    const float* x      = (const float*)d_in[0];
    const float* w_attn = (const float*)d_in[1];
    const float* w_proj = (const float*)d_in[2];
    float* out = (float*)d_out;

    unsigned short* ws  = (unsigned short*)d_ws;
    unsigned short* xb  = ws;
    unsigned short* wab = xb + (size_t)LSEQ * EMB;
    unsigned short* wpb = wab + (size_t)3 * EMB * EMB;
    unsigned short* Qb  = wpb + (size_t)EMB * EMB;
    unsigned short* Kb  = Qb + (size_t)LSEQ * EMB;
    unsigned short* Vtb = Kb + (size_t)LSEQ * EMB;
    unsigned short* Yb  = Vtb + (size_t)LSEQ * EMB;

    const int ntot = NXC + NAC + NPC;
    cvt_all<<<(ntot + 255) / 256, 256, 0, stream>>>(x, w_attn, w_proj, xb);
    gemm_qkv<<<dim3(3 * EMB / 128, LSEQ / 128), 256, 0, stream>>>(xb, wab, Qb, Kb, Vtb);
    attn_fwd<<<dim3(512), 256, 0, stream>>>(Qb, Kb, Vtb, Yb);
    gemm_proj<<<dim3(EMB / 128, LSEQ / 128), 256, 0, stream>>>(Yb, wpb, out);
}